// Round 2
// baseline (276.186 us; speedup 1.0000x reference)
//
#include <hip/hip_runtime.h>
#include <hip/hip_bf16.h>

typedef __attribute__((ext_vector_type(8))) short bf16x8;
typedef __attribute__((ext_vector_type(4))) float f32x4;

#define L_SEQ 512
#define N_IN 12
#define S_DIM 128
#define M_OUT 12

#define A_STRIDE 136   // 272B row stride -> <=2-way banks on b128 reads / b16 writes
#define X_STRIDE 40    // 80B row stride

__device__ inline short f2bf(float f) {            // RNE (cold path)
    union { float f; unsigned u; } q; q.f = f;
    unsigned r = (q.u + 0x7fffu + ((q.u >> 16) & 1u)) >> 16;
    return (short)r;
}
__device__ inline short f2bf_fast(float f) {       // round-half-up (hot path)
    union { float f; unsigned u; } q; q.f = f;
    return (short)((q.u + 0x8000u) >> 16);
}

__device__ inline void block_sync() {
    asm volatile("s_waitcnt lgkmcnt(0)" ::: "memory");
    __builtin_amdgcn_s_barrier();
}

__global__ __launch_bounds__(128, 1)
void elman_kernel(const float* __restrict__ x,
                  const float* __restrict__ a0,
                  const float* __restrict__ U_w,
                  const float* __restrict__ U_b,
                  const float* __restrict__ W_w,
                  const float* __restrict__ W_b,
                  const float* __restrict__ V_w,
                  const float* __restrict__ V_b,
                  float* __restrict__ out)
{
    __shared__ __align__(16) short a_lds[2][16][A_STRIDE];
    __shared__ __align__(16) short x_lds[4][16][X_STRIDE];

    const int tid  = threadIdx.x;
    const int w    = tid >> 6;       // wave 0..1
    const int l    = tid & 63;
    const int b0   = blockIdx.x * 16;
    const int lrow = l & 15;
    const int lk8  = (l >> 4) * 8;

    // ---- step-invariant fragments: W (4 col-tiles x 4 k-tiles), U, bias ----
    bf16x8 wf[4][4]; bf16x8 uf[4]; float biasc[4];
    #pragma unroll
    for (int ct = 0; ct < 4; ++ct) {
        const int c = w * 64 + ct * 16 + lrow;
        #pragma unroll
        for (int kt = 0; kt < 4; ++kt)
            #pragma unroll
            for (int j = 0; j < 8; ++j)
                wf[ct][kt][j] = f2bf(W_w[(kt * 32 + lk8 + j) * S_DIM + c]);
        #pragma unroll
        for (int j = 0; j < 8; ++j) {
            int k = lk8 + j;
            uf[ct][j] = (k < N_IN) ? f2bf(U_w[k * S_DIM + c]) : (short)0;
        }
        biasc[ct] = W_b[c] + U_b[c];
    }

    // ---- zero x_lds pad region (cols 12..31; 0..11 staged, 32..39 never read) ----
    for (int i = tid; i < 4 * 16 * 20; i += 128) {
        int buf = i / 320, rem = i % 320;
        x_lds[buf][rem / 20][12 + rem % 20] = 0;
    }

    // ---- stage a0 (bf16) ----
    for (int i = tid; i < 16 * 32; i += 128) {
        int r = i >> 5, q = i & 31;
        const float4 v = *(const float4*)&a0[(size_t)(b0 + r) * S_DIM + q * 4];
        short* dst = &a_lds[0][r][q * 4];
        dst[0] = f2bf(v.x); dst[1] = f2bf(v.y); dst[2] = f2bf(v.z); dst[3] = f2bf(v.w);
    }

    // ---- stage x_0..x_3 into ring bufs 0..3 ----
    for (int s = tid; s < 192; s += 128) {
        int buf = s / 48, r = (s % 48) / 3, p = s % 3;
        const float4 v = *(const float4*)&x[((size_t)(b0 + r) * L_SEQ + buf) * N_IN + p * 4];
        short* dst = &x_lds[buf][r][p * 4];
        dst[0] = f2bf(v.x); dst[1] = f2bf(v.y); dst[2] = f2bf(v.z); dst[3] = f2bf(v.w);
    }

    // ---- x prefetch: wave w owns rows w*8..w*8+7 (24 lanes x float4), every step:
    //      write x_{t+2} (loaded 2 steps ago), load x_{t+4}. ----
    const int qrow  = w * 8 + l / 3;   // valid for l < 24
    const int spart = l % 3;
    float4 qa, qb;                     // qa -> even-distance, alternate to keep 2-step latency
    if (l < 24) {
        qa = *(const float4*)&x[((size_t)(b0 + qrow) * L_SEQ + 2) * N_IN + spart * 4]; // x_2
        qb = *(const float4*)&x[((size_t)(b0 + qrow) * L_SEQ + 3) * N_IN + spart * 4]; // x_3
    }

    block_sync();

    // ---- accx for t=0: bias + x_0 @ U ----
    f32x4 accx[4];
    {
        bf16x8 xf = *(const bf16x8*)&x_lds[0][lrow][lk8];
        #pragma unroll
        for (int ct = 0; ct < 4; ++ct) {
            f32x4 b = {biasc[ct], biasc[ct], biasc[ct], biasc[ct]};
            accx[ct] = __builtin_amdgcn_mfma_f32_16x16x32_bf16(xf, uf[ct], b, 0, 0, 0);
        }
    }

    // ---- main recurrence (unrolled x2 so qa/qb rotate with static names) ----
    for (int t = 0; t < L_SEQ; t += 2) {
        #pragma unroll
        for (int half = 0; half < 2; ++half) {
            const int tt = t + half;
            const int p = tt & 1;
            const short* abase = &a_lds[p][lrow][0];
            bf16x8 af0 = *(const bf16x8*)(abase + lk8);
            bf16x8 af1 = *(const bf16x8*)(abase + 32 + lk8);
            bf16x8 af2 = *(const bf16x8*)(abase + 64 + lk8);
            bf16x8 af3 = *(const bf16x8*)(abase + 96 + lk8);

            #pragma unroll
            for (int ct = 0; ct < 4; ++ct) {
                f32x4 r0 = __builtin_amdgcn_mfma_f32_16x16x32_bf16(af0, wf[ct][0], accx[ct], 0, 0, 0);
                r0 = __builtin_amdgcn_mfma_f32_16x16x32_bf16(af1, wf[ct][1], r0, 0, 0, 0);
                f32x4 z = {0.f, 0.f, 0.f, 0.f};
                f32x4 r1 = __builtin_amdgcn_mfma_f32_16x16x32_bf16(af2, wf[ct][2], z, 0, 0, 0);
                r1 = __builtin_amdgcn_mfma_f32_16x16x32_bf16(af3, wf[ct][3], r1, 0, 0, 0);
                const int c = w * 64 + ct * 16 + lrow;
                #pragma unroll
                for (int j = 0; j < 4; ++j) {
                    float v = fmaxf(r0[j] + r1[j], 0.f);
                    a_lds[p ^ 1][(l >> 4) * 4 + j][c] = f2bf_fast(v);
                }
            }

            // x ring: write x_{tt+2} (in qa if tt even, qb if tt odd; loaded 2 steps ago),
            // then reload that register with x_{tt+4}.
            if (l < 24) {
                float4& q = (half == 0) ? qa : qb;   // static by unroll
                short* dst = &x_lds[(tt + 2) & 3][qrow][spart * 4];
                dst[0] = f2bf_fast(q.x); dst[1] = f2bf_fast(q.y);
                dst[2] = f2bf_fast(q.z); dst[3] = f2bf_fast(q.w);
                int tl = (tt + 4 < L_SEQ) ? (tt + 4) : (L_SEQ - 1);
                q = *(const float4*)&x[((size_t)(b0 + qrow) * L_SEQ + tl) * N_IN + spart * 4];
            }

            // next-step x@U (independent of a_{tt+1}; issues before the barrier)
            {
                bf16x8 xf = *(const bf16x8*)&x_lds[(tt + 1) & 3][lrow][lk8];
                #pragma unroll
                for (int ct = 0; ct < 4; ++ct) {
                    f32x4 b = {biasc[ct], biasc[ct], biasc[ct], biasc[ct]};
                    accx[ct] = __builtin_amdgcn_mfma_f32_16x16x32_bf16(xf, uf[ct], b, 0, 0, 0);
                }
            }
            block_sync();
        }
    }

    // ---- epilogue: y = a_L @ V + V_b (a_L in a_lds[0]); wave 0 only ----
    if (w == 0) {
        bf16x8 vf0, vf1, vf2, vf3;
        #pragma unroll
        for (int j = 0; j < 8; ++j) {
            int cc = lrow;
            vf0[j] = (cc < M_OUT) ? f2bf(V_w[(0  + lk8 + j) * M_OUT + cc]) : (short)0;
            vf1[j] = (cc < M_OUT) ? f2bf(V_w[(32 + lk8 + j) * M_OUT + cc]) : (short)0;
            vf2[j] = (cc < M_OUT) ? f2bf(V_w[(64 + lk8 + j) * M_OUT + cc]) : (short)0;
            vf3[j] = (cc < M_OUT) ? f2bf(V_w[(96 + lk8 + j) * M_OUT + cc]) : (short)0;
        }
        const short* abase = &a_lds[0][lrow][0];
        bf16x8 af0 = *(const bf16x8*)(abase + lk8);
        bf16x8 af1 = *(const bf16x8*)(abase + 32 + lk8);
        bf16x8 af2 = *(const bf16x8*)(abase + 64 + lk8);
        bf16x8 af3 = *(const bf16x8*)(abase + 96 + lk8);
        f32x4 acc = {0.f, 0.f, 0.f, 0.f};
        acc = __builtin_amdgcn_mfma_f32_16x16x32_bf16(af0, vf0, acc, 0, 0, 0);
        acc = __builtin_amdgcn_mfma_f32_16x16x32_bf16(af1, vf1, acc, 0, 0, 0);
        acc = __builtin_amdgcn_mfma_f32_16x16x32_bf16(af2, vf2, acc, 0, 0, 0);
        acc = __builtin_amdgcn_mfma_f32_16x16x32_bf16(af3, vf3, acc, 0, 0, 0);
        if (lrow < M_OUT) {
            const float vb = V_b[lrow];
            #pragma unroll
            for (int j = 0; j < 4; ++j) {
                out[(size_t)(b0 + (l >> 4) * 4 + j) * M_OUT + lrow] = acc[j] + vb;
            }
        }
    }
}

extern "C" void kernel_launch(void* const* d_in, const int* in_sizes, int n_in,
                              void* d_out, int out_size, void* d_ws, size_t ws_size,
                              hipStream_t stream) {
    const float* x   = (const float*)d_in[0];
    const float* a0  = (const float*)d_in[1];
    const float* U_w = (const float*)d_in[2];
    const float* U_b = (const float*)d_in[3];
    const float* W_w = (const float*)d_in[4];
    const float* W_b = (const float*)d_in[5];
    const float* V_w = (const float*)d_in[6];
    const float* V_b = (const float*)d_in[7];
    float* out = (float*)d_out;

    hipLaunchKernelGGL(elman_kernel, dim3(4096 / 16), dim3(128), 0, stream,
                       x, a0, U_w, U_b, W_w, W_b, V_w, V_b, out);
}